// Round 5
// baseline (1684.813 us; speedup 1.0000x reference)
//
#include <hip/hip_runtime.h>
#include <math.h>

#define KN 1024
#define KB 128
#define KDT 0.1f
#define KSTEPS 10

typedef __attribute__((ext_vector_type(8))) short short8;
typedef __attribute__((ext_vector_type(4))) float floatx4;

__device__ __forceinline__ unsigned short f2bf(float f) {
    unsigned u = __float_as_uint(f);
    u += 0x7FFF + ((u >> 16) & 1);          // round-to-nearest-even
    return (unsigned short)(u >> 16);
}

// Zero barrier counters + coherence accumulators (ws is poisoned 0xAA each launch).
__global__ __launch_bounds__(256)
void k_zero(unsigned* __restrict__ bar, float* __restrict__ ssum, float* __restrict__ csum)
{
    int t = threadIdx.x;
    bar[t] = 0u;            // 8 groups use stride-32 slots (128 B apart)
    ssum[t] = 0.f;
    csum[t] = 0.f;
}

// Persistent fused kernel, PLAIN launch (graph-capturable).
// Grid 256 = 8 batch-groups x 32 i-blocks; block 1024 thr = 16 waves.
// Wave: wi = i-subtile (16 cols), kq = K-eighth (128 k).
// Each wave holds its K slice as bf16 MFMA B-fragments in REGISTERS for the
// whole kernel (16 VGPRs) — K is read from HBM exactly once.
__global__ __launch_bounds__(1024)
void k_main(const float* __restrict__ theta0,
            const float* __restrict__ Kmat,
            const float* __restrict__ omega,
            const float* __restrict__ kg,
            float* __restrict__ out_theta,
            float* __restrict__ out_coh,
            unsigned* __restrict__ bar,
            float* __restrict__ ssum,
            float* __restrict__ csum,
            unsigned short* __restrict__ xA,
            unsigned short* __restrict__ xB)
{
    const int grp = blockIdx.x >> 5;        // batch-chunk 0..7
    const int b0  = grp * 16;
    const int i0  = (blockIdx.x & 31) * 32;

    const int tid  = threadIdx.x;
    const int lane = tid & 63;
    const int wave = tid >> 6;
    const int wi   = wave & 1;
    const int kq   = wave >> 1;             // 0..7
    const int r16  = lane & 15;
    const int quad = lane >> 4;
    const int kbase = kq * 128 + quad * 8;

    __shared__ float ldsY[8][2][16][34];    // 34.8 KB partial sums (+pad)

    // ---- prologue: B fragments fp32->bf16 into registers (K symmetric:
    // row i of K supplies B-column i with contiguous-k loads).
    short8 bfrag[4];
    {
        const float* kp = Kmat + (size_t)(i0 + wi * 16 + r16) * KN + kbase;
        #pragma unroll
        for (int it = 0; it < 4; ++it) {
            const float4 v0 = *reinterpret_cast<const float4*>(kp + it * 32);
            const float4 v1 = *reinterpret_cast<const float4*>(kp + it * 32 + 4);
            short8 b_;
            b_[0] = (short)f2bf(v0.x); b_[1] = (short)f2bf(v0.y);
            b_[2] = (short)f2bf(v0.z); b_[3] = (short)f2bf(v0.w);
            b_[4] = (short)f2bf(v1.x); b_[5] = (short)f2bf(v1.y);
            b_[6] = (short)f2bf(v1.z); b_[7] = (short)f2bf(v1.w);
            bfrag[it] = b_;
        }
    }

    // ---- epilogue-thread state: theta tile is block-private -> register
    float th_reg = 0.f, omg = 0.f;
    int eb = 0, ei = 0;
    if (tid < 512) {
        eb = b0 + (tid >> 5);
        ei = i0 + (tid & 31);
        th_reg = theta0[(size_t)eb * KN + ei];
        omg = omega[ei];
        float s, c;
        __sincosf(th_reg, &s, &c);
        xA[(size_t)eb * KN + ei]        = f2bf(s);
        xA[(size_t)(KB + eb) * KN + ei] = f2bf(c);
    }
    const float scale = kg[0] * (1.0f / (float)KN);

    unsigned nbar = 0;
    unsigned* mybar = &bar[grp * 32];       // own 128 B line per group
    auto group_barrier = [&]() {
        ++nbar;
        __threadfence();                    // release: X writes visible device-wide
        __syncthreads();
        if (tid == 0) {
            __hip_atomic_fetch_add(mybar, 1u, __ATOMIC_ACQ_REL, __HIP_MEMORY_SCOPE_AGENT);
            const unsigned target = 32u * nbar;
            unsigned spins = 0;
            while (__hip_atomic_load(mybar, __ATOMIC_ACQUIRE, __HIP_MEMORY_SCOPE_AGENT) < target) {
                __builtin_amdgcn_s_sleep(4);
                if (++spins > 10000000u) break;   // ~1 s failsafe: fail visibly, not hang
            }
        }
        __syncthreads();
        __threadfence();                    // acquire: drop stale lines before X reads
    };

    auto do_gemm = [&](const unsigned short* __restrict__ xin) {
        floatx4 accS = {0.f, 0.f, 0.f, 0.f};
        floatx4 accC = {0.f, 0.f, 0.f, 0.f};
        const unsigned short* aS = xin + (size_t)(b0 + r16) * KN + kbase;
        const unsigned short* aC = xin + (size_t)(KB + b0 + r16) * KN + kbase;
        #pragma unroll
        for (int it = 0; it < 4; ++it) {
            short8 a_s = *(const short8*)(aS + it * 32);
            short8 a_c = *(const short8*)(aC + it * 32);
            accS = __builtin_amdgcn_mfma_f32_16x16x32_bf16(a_s, bfrag[it], accS, 0, 0, 0);
            accC = __builtin_amdgcn_mfma_f32_16x16x32_bf16(a_c, bfrag[it], accC, 0, 0, 0);
        }
        const int il = wi * 16 + r16;
        #pragma unroll
        for (int r = 0; r < 4; ++r) {
            ldsY[kq][0][quad * 4 + r][il] = accS[r];   // D[m=quad*4+r][n=lane&15]
            ldsY[kq][1][quad * 4 + r][il] = accC[r];
        }
    };

    auto do_update = [&](float& s2, float& c2) {       // tid<512 only
        const int bl = tid >> 5, il = tid & 31;
        float Ys = 0.f, Yc = 0.f;
        #pragma unroll
        for (int q = 0; q < 8; ++q) {
            Ys += ldsY[q][0][bl][il];
            Yc += ldsY[q][1][bl][il];
        }
        float sn, cs;
        __sincosf(th_reg, &sn, &cs);
        const float coupling = cs * Ys - sn * Yc;      // sum_j K[i,j] sin(th_j - th_i)
        float tn = th_reg + KDT * (omg + scale * coupling);
        s2 = __sinf(tn);
        c2 = __cosf(tn);
        th_reg = atan2f(s2, c2);                        // wrap to (-pi, pi]
    };

    group_barrier();                        // nbar=1: X init ready

    unsigned short* xcur = xA;
    unsigned short* xnxt = xB;
    for (int s = 0; s < KSTEPS - 1; ++s) {
        do_gemm(xcur);
        __syncthreads();
        if (tid < 512) {
            float s2, c2;
            do_update(s2, c2);
            xnxt[(size_t)eb * KN + ei]        = f2bf(s2);
            xnxt[(size_t)(KB + eb) * KN + ei] = f2bf(c2);
        }
        group_barrier();                    // nbar = 2..10
        unsigned short* t = xcur; xcur = xnxt; xnxt = t;
    }

    // ---- final step: write theta, fold in coherence
    do_gemm(xcur);
    __syncthreads();
    float s2 = 0.f, c2 = 0.f;
    if (tid < 512) {
        do_update(s2, c2);
        out_theta[(size_t)eb * KN + ei] = th_reg;
    }
    __syncthreads();                        // all ldsY reads done before reuse
    float* red = &ldsY[0][0][0][0];
    if (tid < 512) {
        red[tid]       = s2;                // sin(theta_final) to ~1e-7
        red[512 + tid] = c2;
    }
    __syncthreads();
    if (tid < 16) {
        float ss = 0.f, cc = 0.f;
        #pragma unroll
        for (int il2 = 0; il2 < 32; ++il2) {
            ss += red[tid * 32 + il2];
            cc += red[512 + tid * 32 + il2];
        }
        atomicAdd(&ssum[b0 + tid], ss);     // device-scope by default
        atomicAdd(&csum[b0 + tid], cc);
    }
    group_barrier();                        // nbar = 11: group's atomics visible
    if ((blockIdx.x & 31) == 0 && tid < 16) {
        float sv = __hip_atomic_load(&ssum[b0 + tid], __ATOMIC_RELAXED, __HIP_MEMORY_SCOPE_AGENT);
        float cv = __hip_atomic_load(&csum[b0 + tid], __ATOMIC_RELAXED, __HIP_MEMORY_SCOPE_AGENT);
        float sm = sv * (1.0f / (float)KN);
        float cm = cv * (1.0f / (float)KN);
        out_coh[b0 + tid] = sqrtf(cm * cm + sm * sm);
    }
}

extern "C" void kernel_launch(void* const* d_in, const int* in_sizes, int n_in,
                              void* d_out, int out_size, void* d_ws, size_t ws_size,
                              hipStream_t stream)
{
    (void)in_sizes; (void)n_in; (void)out_size; (void)ws_size;

    const float* theta0 = (const float*)d_in[0];
    const float* Kmat   = (const float*)d_in[1];
    const float* omega  = (const float*)d_in[2];
    const float* kg     = (const float*)d_in[3];

    float* out_theta = (float*)d_out;                    // 128*1024 f32
    float* out_coh   = out_theta + (size_t)KB * KN;      // +128 f32

    // ws: bar[256] u32 | ssum[256] f32 | csum[256] f32 | pad | xA 512K | xB 512K
    unsigned* bar = (unsigned*)d_ws;
    float* ssum   = (float*)((char*)d_ws + 1024);
    float* csum   = (float*)((char*)d_ws + 2048);
    unsigned short* xA = (unsigned short*)((char*)d_ws + 4096);
    unsigned short* xB = xA + (size_t)2 * KB * KN;

    k_zero<<<1, 256, 0, stream>>>(bar, ssum, csum);
    k_main<<<256, 1024, 0, stream>>>(theta0, Kmat, omega, kg,
                                     out_theta, out_coh,
                                     bar, ssum, csum, xA, xB);
}

// Round 6
// 226.176 us; speedup vs baseline: 7.4491x; 7.4491x over previous
//
#include <hip/hip_runtime.h>
#include <math.h>

#define KN 1024
#define KB 128
#define KDT 0.1f
#define KSTEPS 10
#define KMAGIC 0x5A170000u

typedef __attribute__((ext_vector_type(8))) short short8;
typedef __attribute__((ext_vector_type(4))) float floatx4;

__device__ __forceinline__ unsigned short f2bf(float f) {
    unsigned u = __float_as_uint(f);
    u += 0x7FFF + ((u >> 16) & 1);          // round-to-nearest-even
    return (unsigned short)(u >> 16);
}

// Single persistent-style kernel, plain launch (graph-capturable).
// Grid 256 = 8 batch-groups(16 batches) x 32 i-blocks(32 cols); block = 16 waves.
// Wave: wi = i-subtile(16 cols), kq = K-eighth(128 k). K lives in registers.
// X exchanged as packed {sin,cos} bf16 u32 via relaxed AGENT atomics (sc-flagged,
// L3-coherent) — NO threadfence / cache-flush anywhere (R5 lesson: fences = 150us).
__global__ __launch_bounds__(1024)
void k_main(const float* __restrict__ theta0,
            const float* __restrict__ Kmat,
            const float* __restrict__ omega,
            const float* __restrict__ kg,
            float* __restrict__ out_theta,
            float* __restrict__ out_coh,
            unsigned* __restrict__ slots,        // 256 per-block phase slots
            unsigned* __restrict__ xA,           // packed X ping
            unsigned* __restrict__ xB)           // packed X pong
{
    const int grp = blockIdx.x >> 5;        // batch-chunk 0..7
    const int b0  = grp * 16;
    const int i0  = (blockIdx.x & 31) * 32;

    const int tid  = threadIdx.x;
    const int lane = tid & 63;
    const int wave = tid >> 6;
    const int wi   = wave & 1;
    const int kq   = wave >> 1;             // 0..7
    const int r16  = lane & 15;
    const int quad = lane >> 4;
    const int kbase = kq * 128 + quad * 8;

    __shared__ float ldsY[8][2][16][34];    // 34.8 KB partial sums (+pad)

    // Publish phase 0 immediately: barrier scheme independent of ws poison value.
    if (tid == 0)
        __hip_atomic_store(&slots[blockIdx.x], KMAGIC, __ATOMIC_RELAXED,
                           __HIP_MEMORY_SCOPE_AGENT);

    // ---- B fragments fp32->bf16 into registers (K symmetric: row i = B col i).
    short8 bfrag[4];
    {
        const float* kp = Kmat + (size_t)(i0 + wi * 16 + r16) * KN + kbase;
        #pragma unroll
        for (int it = 0; it < 4; ++it) {
            const float4 v0 = *reinterpret_cast<const float4*>(kp + it * 32);
            const float4 v1 = *reinterpret_cast<const float4*>(kp + it * 32 + 4);
            short8 b_;
            b_[0] = (short)f2bf(v0.x); b_[1] = (short)f2bf(v0.y);
            b_[2] = (short)f2bf(v0.z); b_[3] = (short)f2bf(v0.w);
            b_[4] = (short)f2bf(v1.x); b_[5] = (short)f2bf(v1.y);
            b_[6] = (short)f2bf(v1.z); b_[7] = (short)f2bf(v1.w);
            bfrag[it] = b_;
        }
    }

    // ---- epilogue-thread state (block-private theta tile in a register)
    float th_reg = 0.f, omg = 0.f;
    int eb = 0, ei = 0;
    if (tid < 512) {
        eb = b0 + (tid >> 5);
        ei = i0 + (tid & 31);
        th_reg = theta0[(size_t)eb * KN + ei];
        omg = omega[ei];
        float s, c;
        __sincosf(th_reg, &s, &c);
        unsigned pack = (unsigned)f2bf(s) | ((unsigned)f2bf(c) << 16);
        __hip_atomic_store(&xA[(size_t)eb * KN + ei], pack, __ATOMIC_RELAXED,
                           __HIP_MEMORY_SCOPE_AGENT);
    }
    const float scale = kg[0] * (1.0f / (float)KN);

    unsigned nbar = 0;
    // Fence-free group barrier: __syncthreads() drains each wave's coherent X
    // stores (compiler emits s_waitcnt vmcnt(0) before s_barrier); then publish
    // phase; wave 0 lanes 0..31 poll the group's 32 slots for equality.
    auto arrive_wait = [&]() {
        ++nbar;
        __syncthreads();
        if (tid == 0)
            __hip_atomic_store(&slots[blockIdx.x], KMAGIC + nbar,
                               __ATOMIC_RELAXED, __HIP_MEMORY_SCOPE_AGENT);
        if (wave == 0) {
            const unsigned expect = KMAGIC + nbar;
            unsigned polls = 0;
            for (;;) {
                unsigned v = expect;
                if (lane < 32)
                    v = __hip_atomic_load(&slots[grp * 32 + lane],
                                          __ATOMIC_RELAXED, __HIP_MEMORY_SCOPE_AGENT);
                if (__ballot(v == expect) == ~0ull) break;
                if (++polls > 2000000u) break;      // ~0.5 s failsafe: fail visibly
                __builtin_amdgcn_s_sleep(2);
            }
        }
        __syncthreads();
    };

    arrive_wait();                          // phase 1: X init visible

    const unsigned* xcur = xA;
    unsigned* xnxt = xB;
    for (int s = 0; s < KSTEPS; ++s) {
        // ---- GEMM: stage all A dwords (coherent), then extract + MFMA
        unsigned aw[4][8];
        {
            const unsigned* ap = xcur + (size_t)(b0 + r16) * KN + kbase;
            #pragma unroll
            for (int it = 0; it < 4; ++it)
                #pragma unroll
                for (int j = 0; j < 8; ++j)
                    aw[it][j] = __hip_atomic_load((unsigned*)(ap + it * 32 + j),
                                                  __ATOMIC_RELAXED,
                                                  __HIP_MEMORY_SCOPE_AGENT);
        }
        floatx4 accS = {0.f, 0.f, 0.f, 0.f};
        floatx4 accC = {0.f, 0.f, 0.f, 0.f};
        #pragma unroll
        for (int it = 0; it < 4; ++it) {
            short8 a_s, a_c;
            #pragma unroll
            for (int j = 0; j < 8; ++j) {
                a_s[j] = (short)(aw[it][j] & 0xffffu);
                a_c[j] = (short)(aw[it][j] >> 16);
            }
            accS = __builtin_amdgcn_mfma_f32_16x16x32_bf16(a_s, bfrag[it], accS, 0, 0, 0);
            accC = __builtin_amdgcn_mfma_f32_16x16x32_bf16(a_c, bfrag[it], accC, 0, 0, 0);
        }
        const int il = wi * 16 + r16;
        #pragma unroll
        for (int r = 0; r < 4; ++r) {
            ldsY[kq][0][quad * 4 + r][il] = accS[r];   // D[m=quad*4+r][n=lane&15]
            ldsY[kq][1][quad * 4 + r][il] = accC[r];
        }
        __syncthreads();

        // ---- Euler update + wrap + publish next X
        if (tid < 512) {
            const int bl = tid >> 5, ilo = tid & 31;
            float Ys = 0.f, Yc = 0.f;
            #pragma unroll
            for (int q = 0; q < 8; ++q) {
                Ys += ldsY[q][0][bl][ilo];
                Yc += ldsY[q][1][bl][ilo];
            }
            float sn, cs;
            __sincosf(th_reg, &sn, &cs);
            const float coupling = cs * Ys - sn * Yc;  // sum_j K[i,j] sin(th_j - th_i)
            float tn = th_reg + KDT * (omg + scale * coupling);
            float s2 = __sinf(tn), c2 = __cosf(tn);
            th_reg = atan2f(s2, c2);                   // wrap to (-pi, pi]
            unsigned pack = (unsigned)f2bf(s2) | ((unsigned)f2bf(c2) << 16);
            __hip_atomic_store(&xnxt[(size_t)eb * KN + ei], pack,
                               __ATOMIC_RELAXED, __HIP_MEMORY_SCOPE_AGENT);
            if (s == KSTEPS - 1)
                out_theta[(size_t)eb * KN + ei] = th_reg;
        }
        arrive_wait();                      // phases 2..11

        const unsigned* t = xcur; xcur = xnxt; xnxt = (unsigned*)t;
    }

    // ---- coherence: group's i-block 0 reads final packed X (bf16 sin/cos)
    if ((blockIdx.x & 31) == 0) {
        const int bl = tid >> 6;            // 0..15 batch
        const unsigned* xp = xcur + (size_t)(b0 + bl) * KN;
        float ss = 0.f, cc = 0.f;
        #pragma unroll
        for (int k2 = 0; k2 < 16; ++k2) {
            unsigned u = __hip_atomic_load((unsigned*)(xp + lane + 64 * k2),
                                           __ATOMIC_RELAXED, __HIP_MEMORY_SCOPE_AGENT);
            ss += __uint_as_float(u << 16);            // bf16 sin -> f32
            cc += __uint_as_float(u & 0xffff0000u);    // bf16 cos -> f32
        }
        #pragma unroll
        for (int off = 32; off > 0; off >>= 1) {
            ss += __shfl_down(ss, off);
            cc += __shfl_down(cc, off);
        }
        if (lane == 0) {
            float sm = ss * (1.0f / (float)KN);
            float cm = cc * (1.0f / (float)KN);
            out_coh[b0 + bl] = sqrtf(cm * cm + sm * sm);
        }
    }
}

extern "C" void kernel_launch(void* const* d_in, const int* in_sizes, int n_in,
                              void* d_out, int out_size, void* d_ws, size_t ws_size,
                              hipStream_t stream)
{
    (void)in_sizes; (void)n_in; (void)out_size; (void)ws_size;

    const float* theta0 = (const float*)d_in[0];
    const float* Kmat   = (const float*)d_in[1];
    const float* omega  = (const float*)d_in[2];
    const float* kg     = (const float*)d_in[3];

    float* out_theta = (float*)d_out;                    // 128*1024 f32
    float* out_coh   = out_theta + (size_t)KB * KN;      // +128 f32

    // ws: slots[256] u32 | pad to 4 KB | xA 512 KB | xB 512 KB
    unsigned* slots = (unsigned*)d_ws;
    unsigned* xA = (unsigned*)((char*)d_ws + 4096);
    unsigned* xB = xA + (size_t)KB * KN;

    k_main<<<256, 1024, 0, stream>>>(theta0, Kmat, omega, kg,
                                     out_theta, out_coh, slots, xA, xB);
}

// Round 7
// 98.366 us; speedup vs baseline: 17.1280x; 2.2993x over previous
//
#include <hip/hip_runtime.h>
#include <math.h>

#define KN 1024
#define KB 128
#define KDT 0.1f
#define KSTEPS 10
#define KMAGIC 0x5A170000u

typedef __attribute__((ext_vector_type(8))) short short8;
typedef __attribute__((ext_vector_type(4))) float floatx4;
typedef unsigned long long u64;

__device__ __forceinline__ unsigned short f2bf(float f) {
    unsigned u = __float_as_uint(f);
    u += 0x7FFF + ((u >> 16) & 1);          // round-to-nearest-even
    return (unsigned short)(u >> 16);
}

// X layout (fragment order, per group g = b>>4; 16384 dwords per group).
// Element (b15 = b&15, k): chunk=k>>5, quad=(k>>3)&3, jj=(k>>1)&3, p=k&1
//   dword idx = g*16384 + chunk*512 + jj*128 + quad*32 + b15*2 + p
// Consumer wave kq, lane L (r16=L&15, quad=L>>4), it, jj reads u64 at
//   g*8192 + (kq*4+it)*256 + jj*64 + L   -> dense 512 B per wave instruction.
__device__ __forceinline__ unsigned xidx(int grp, int b15, int k) {
    return (unsigned)(grp * 16384 + (k >> 5) * 512 + ((k >> 1) & 3) * 128 +
                      ((k >> 3) & 3) * 32 + b15 * 2 + (k & 1));
}

// Single kernel, plain launch (graph-capturable).
// Grid 256 = 8 batch-groups(16 b) x 32 i-blocks(32 cols); block 512 thr = 8 waves.
// Wave = kq (k-eighth, 128 k), computes BOTH wi 16-col subtiles (no A duplication).
// K lives in registers (read once). X exchanged via relaxed agent atomics (sc1,
// L3-coherent, no fences — R5 lesson). Barrier = per-block phase slots (R6).
__global__ __launch_bounds__(512)
void k_main(const float* __restrict__ theta0,
            const float* __restrict__ Kmat,
            const float* __restrict__ omega,
            const float* __restrict__ kg,
            float* __restrict__ out_theta,
            float* __restrict__ out_coh,
            unsigned* __restrict__ slots,        // 256 per-block phase slots
            float* __restrict__ acc,             // coherence accum: 2*128 slots, 64B stride
            unsigned* __restrict__ xA,
            unsigned* __restrict__ xB)
{
    const int grp = blockIdx.x >> 5;
    const int b0  = grp * 16;
    const int i0  = (blockIdx.x & 31) * 32;

    const int tid  = threadIdx.x;
    const int lane = tid & 63;
    const int kq   = tid >> 6;              // wave = k-eighth
    const int r16  = lane & 15;
    const int quad = lane >> 4;

    __shared__ float ldsY[8][2][16][34];    // [kq][S/C][m][il+pad] 34.8 KB

    // phase-0 publish (barrier independent of ws poison)
    if (tid == 0)
        __hip_atomic_store(&slots[blockIdx.x], KMAGIC, __ATOMIC_RELAXED,
                           __HIP_MEMORY_SCOPE_AGENT);
    // group leader zeroes its coherence accumulators (64 B stride slots)
    if ((blockIdx.x & 31) == 0 && tid < 16) {
        __hip_atomic_store(&acc[(b0 + tid) * 16], 0.f, __ATOMIC_RELAXED,
                           __HIP_MEMORY_SCOPE_AGENT);
        __hip_atomic_store(&acc[2048 + (b0 + tid) * 16], 0.f, __ATOMIC_RELAXED,
                           __HIP_MEMORY_SCOPE_AGENT);
    }

    // ---- B fragments (both wi) fp32->bf16 into registers; K symmetric.
    short8 bfrag[2][4];
    #pragma unroll
    for (int wi = 0; wi < 2; ++wi) {
        const float* kp = Kmat + (size_t)(i0 + wi * 16 + r16) * KN + kq * 128 + quad * 8;
        #pragma unroll
        for (int it = 0; it < 4; ++it) {
            const float4 v0 = *reinterpret_cast<const float4*>(kp + it * 32);
            const float4 v1 = *reinterpret_cast<const float4*>(kp + it * 32 + 4);
            short8 b_;
            b_[0] = (short)f2bf(v0.x); b_[1] = (short)f2bf(v0.y);
            b_[2] = (short)f2bf(v0.z); b_[3] = (short)f2bf(v0.w);
            b_[4] = (short)f2bf(v1.x); b_[5] = (short)f2bf(v1.y);
            b_[6] = (short)f2bf(v1.z); b_[7] = (short)f2bf(v1.w);
            bfrag[wi][it] = b_;
        }
    }

    // ---- per-thread theta state (block-private tile, 1 elem/thread)
    const int eb = b0 + (tid >> 5);          // batch
    const int ei = i0 + (tid & 31);          // column
    float th_reg = theta0[(size_t)eb * KN + ei];
    const float omg = omega[ei];
    {
        float s, c;
        __sincosf(th_reg, &s, &c);
        unsigned pack = (unsigned)f2bf(s) | ((unsigned)f2bf(c) << 16);
        __hip_atomic_store(&xA[xidx(grp, eb & 15, ei)], pack, __ATOMIC_RELAXED,
                           __HIP_MEMORY_SCOPE_AGENT);
    }
    const float scale = kg[0] * (1.0f / (float)KN);

    unsigned nbar = 0;
    auto arrive_wait = [&]() {
        ++nbar;
        __syncthreads();                     // drains vmcnt: X stores done
        if (tid == 0)
            __hip_atomic_store(&slots[blockIdx.x], KMAGIC + nbar,
                               __ATOMIC_RELAXED, __HIP_MEMORY_SCOPE_AGENT);
        if (tid < 64) {                      // wave 0 polls the group's 32 slots
            const unsigned expect = KMAGIC + nbar;
            unsigned polls = 0;
            for (;;) {
                unsigned v = expect;
                if (lane < 32)
                    v = __hip_atomic_load(&slots[grp * 32 + lane],
                                          __ATOMIC_RELAXED, __HIP_MEMORY_SCOPE_AGENT);
                if (__ballot(v == expect) == ~0ull) break;
                if (++polls > 2000000u) break;   // failsafe: fail visibly, not hang
                __builtin_amdgcn_s_sleep(2);
            }
        }
        __syncthreads();
    };

    arrive_wait();                           // phase 1: X init visible

    const unsigned* xcur = xA;
    unsigned* xnxt = xB;
    float s2 = 0.f, c2 = 0.f;
    for (int s = 0; s < KSTEPS; ++s) {
        // ---- A stage: 16 dense coherent u64 loads (512 B/wave-instr)
        const u64* xg = (const u64*)xcur + grp * 8192 + kq * 1024 + lane;
        u64 aw[4][4];
        #pragma unroll
        for (int it = 0; it < 4; ++it)
            #pragma unroll
            for (int jj = 0; jj < 4; ++jj)
                aw[it][jj] = __hip_atomic_load((u64*)(xg + it * 256 + jj * 64),
                                               __ATOMIC_RELAXED,
                                               __HIP_MEMORY_SCOPE_AGENT);
        // ---- extract + MFMA (both wi subtiles)
        floatx4 accS[2] = {{0.f,0.f,0.f,0.f},{0.f,0.f,0.f,0.f}};
        floatx4 accC[2] = {{0.f,0.f,0.f,0.f},{0.f,0.f,0.f,0.f}};
        #pragma unroll
        for (int it = 0; it < 4; ++it) {
            short8 a_s, a_c;
            #pragma unroll
            for (int jj = 0; jj < 4; ++jj) {
                unsigned lo = (unsigned)aw[it][jj];
                unsigned hi = (unsigned)(aw[it][jj] >> 32);
                a_s[jj * 2]     = (short)(lo & 0xffffu);
                a_c[jj * 2]     = (short)(lo >> 16);
                a_s[jj * 2 + 1] = (short)(hi & 0xffffu);
                a_c[jj * 2 + 1] = (short)(hi >> 16);
            }
            #pragma unroll
            for (int wi = 0; wi < 2; ++wi) {
                accS[wi] = __builtin_amdgcn_mfma_f32_16x16x32_bf16(a_s, bfrag[wi][it], accS[wi], 0, 0, 0);
                accC[wi] = __builtin_amdgcn_mfma_f32_16x16x32_bf16(a_c, bfrag[wi][it], accC[wi], 0, 0, 0);
            }
        }
        #pragma unroll
        for (int wi = 0; wi < 2; ++wi)
            #pragma unroll
            for (int r = 0; r < 4; ++r) {
                ldsY[kq][0][quad * 4 + r][wi * 16 + r16] = accS[wi][r];  // D[m=quad*4+r][n=r16]
                ldsY[kq][1][quad * 4 + r][wi * 16 + r16] = accC[wi][r];
            }
        __syncthreads();

        // ---- Euler update + wrap (1 elem/thread)
        {
            const int bl = tid >> 5, ilo = tid & 31;
            float Ys = 0.f, Yc = 0.f;
            #pragma unroll
            for (int q = 0; q < 8; ++q) {
                Ys += ldsY[q][0][bl][ilo];
                Yc += ldsY[q][1][bl][ilo];
            }
            float sn, cs;
            __sincosf(th_reg, &sn, &cs);
            const float coupling = cs * Ys - sn * Yc;   // sum_j K[i,j] sin(th_j - th_i)
            float tn = th_reg + KDT * (omg + scale * coupling);
            s2 = __sinf(tn);
            c2 = __cosf(tn);
            th_reg = atan2f(s2, c2);                    // wrap to (-pi, pi]
        }
        if (s < KSTEPS - 1) {
            unsigned pack = (unsigned)f2bf(s2) | ((unsigned)f2bf(c2) << 16);
            __hip_atomic_store(&xnxt[xidx(grp, eb & 15, ei)], pack,
                               __ATOMIC_RELAXED, __HIP_MEMORY_SCOPE_AGENT);
            arrive_wait();                   // phases 2..10
            const unsigned* t = xcur; xcur = xnxt; xnxt = (unsigned*)t;
        } else {
            out_theta[(size_t)eb * KN + ei] = th_reg;
        }
    }

    // ---- coherence: block-local reduce over its 32 cols, then padded atomics
    __syncthreads();
    float* red = &ldsY[0][0][0][0];
    red[tid]       = s2;                     // == sin(theta_final) to ~1e-7
    red[512 + tid] = c2;
    __syncthreads();
    if (tid < 16) {
        float ss = 0.f, cc = 0.f;
        #pragma unroll
        for (int il2 = 0; il2 < 32; ++il2) {
            ss += red[tid * 32 + il2];
            cc += red[512 + tid * 32 + il2];
        }
        atomicAdd(&acc[(b0 + tid) * 16], ss);           // 64B-stride slots
        atomicAdd(&acc[2048 + (b0 + tid) * 16], cc);
    }
    arrive_wait();                           // final phase: group's adds visible
    if ((blockIdx.x & 31) == 0 && tid < 16) {
        float sv = __hip_atomic_load(&acc[(b0 + tid) * 16],
                                     __ATOMIC_RELAXED, __HIP_MEMORY_SCOPE_AGENT);
        float cv = __hip_atomic_load(&acc[2048 + (b0 + tid) * 16],
                                     __ATOMIC_RELAXED, __HIP_MEMORY_SCOPE_AGENT);
        float sm = sv * (1.0f / (float)KN);
        float cm = cv * (1.0f / (float)KN);
        out_coh[b0 + tid] = sqrtf(cm * cm + sm * sm);
    }
}

extern "C" void kernel_launch(void* const* d_in, const int* in_sizes, int n_in,
                              void* d_out, int out_size, void* d_ws, size_t ws_size,
                              hipStream_t stream)
{
    (void)in_sizes; (void)n_in; (void)out_size; (void)ws_size;

    const float* theta0 = (const float*)d_in[0];
    const float* Kmat   = (const float*)d_in[1];
    const float* omega  = (const float*)d_in[2];
    const float* kg     = (const float*)d_in[3];

    float* out_theta = (float*)d_out;                    // 128*1024 f32
    float* out_coh   = out_theta + (size_t)KB * KN;      // +128 f32

    // ws: slots[256] u32 @0 | acc 16 KB @4096 | xA 512 KB | xB 512 KB
    unsigned* slots = (unsigned*)d_ws;
    float* acc      = (float*)((char*)d_ws + 4096);
    unsigned* xA    = (unsigned*)((char*)d_ws + 4096 + 16384);
    unsigned* xB    = xA + (size_t)KB * KN;

    k_main<<<256, 512, 0, stream>>>(theta0, Kmat, omega, kg,
                                    out_theta, out_coh, slots, acc, xA, xB);
}